// Round 1
// baseline (9.714 us; speedup 1.0000x reference)
//
#include <hip/hip_runtime.h>

// NoQmix: softmax over axis=1 makes every column of `attention` sum to 1,
// so q_tot[b] = sum_j agent_qs[b, j] EXACTLY. Everything else (GEMM with W,
// s1/s2, leaky-relu, adj mask, softmax) cancels algebraically.
//
// Inputs (setup_inputs order):
//   d_in[0] features (B,N,F) f32   -- unused
//   d_in[1] agent_qs (B,N)   f32   -- the only live input
//   d_in[2] adj      (N,N)   i32   -- unused
//   d_in[3] states   (B,2048) f32  -- unused
//   d_in[4] W        (F,H)   f32   -- unused
//   d_in[5] a        (2H,1)  f32   -- unused
// Output: (B,1,1) f32, out_size = B = 4096.

#define N_AGENTS 64

__global__ __launch_bounds__(256) void noqmix_rowsum_kernel(
    const float* __restrict__ qs, float* __restrict__ out, int n_rows) {
    // 16 lanes per row, each loads one float4 (coalesced: consecutive lanes
    // read consecutive 16B segments).
    int t = blockIdx.x * blockDim.x + threadIdx.x;
    int row = t >> 4;
    int part = t & 15;
    if (row >= n_rows) return;

    const float4 v = reinterpret_cast<const float4*>(qs)[(size_t)row * 16 + part];
    float s = (v.x + v.y) + (v.z + v.w);

    // Reduce across the 16-lane group (xor masks < 16 stay within the group).
    s += __shfl_xor(s, 1);
    s += __shfl_xor(s, 2);
    s += __shfl_xor(s, 4);
    s += __shfl_xor(s, 8);

    if (part == 0) out[row] = s;
}

extern "C" void kernel_launch(void* const* d_in, const int* in_sizes, int n_in,
                              void* d_out, int out_size, void* d_ws, size_t ws_size,
                              hipStream_t stream) {
    const float* qs = (const float*)d_in[1];   // agent_qs, (B, 64) f32
    float* out = (float*)d_out;                // (B,) f32
    int n_rows = out_size;                     // B = 4096

    int threads_needed = n_rows * 16;          // 16 lanes per row
    int block = 256;
    int grid = (threads_needed + block - 1) / block;
    noqmix_rowsum_kernel<<<grid, block, 0, stream>>>(qs, out, n_rows);
}